// Round 1
// baseline (756.711 us; speedup 1.0000x reference)
//
#include <hip/hip_runtime.h>
#include <hip/hip_bf16.h>

// Problem constants
#define BB 2
#define CC 512
#define HH 14
#define WW 14
#define PP 196      // H*W
#define NSEQ 8      // 4 modes x 2 batches

// ---------------------------------------------------------------------------
// Kernel 0: transpose Wh (512x512) -> WhT so the recurrence matvec reads are
// coalesced (consecutive threads read consecutive output channels).
// ---------------------------------------------------------------------------
__global__ void transpose_wh(const float* __restrict__ Wh, float* __restrict__ WhT) {
    __shared__ float tile[32][33];
    int c0 = blockIdx.x * 32, k0 = blockIdx.y * 32;
    int tx = threadIdx.x % 32, ty = threadIdx.x / 32;   // 32x8
    #pragma unroll
    for (int r = 0; r < 4; ++r)
        tile[ty + 8*r][tx] = Wh[(size_t)(c0 + ty + 8*r) * CC + k0 + tx];
    __syncthreads();
    #pragma unroll
    for (int r = 0; r < 4; ++r)
        WhT[(size_t)(k0 + ty + 8*r) * CC + c0 + tx] = tile[tx][ty + 8*r];
}

// ---------------------------------------------------------------------------
// Kernel 1: A[b][p][c] = sum_k Wx[c][k] * X[b][k][p] + b_in[c]
// 32(c) x 32(p) tiles, K-tiles of 32.
// ---------------------------------------------------------------------------
__global__ __launch_bounds__(256) void gemm_a(
    const float* __restrict__ Wx, const float* __restrict__ X,
    const float* __restrict__ b_in, float* __restrict__ A) {
    __shared__ float Ws[32][33], Xs[32][33];
    int b  = blockIdx.z;
    int c0 = blockIdx.x * 32, p0 = blockIdx.y * 32;
    int t  = threadIdx.x;
    int tx = t % 32, ty = t / 32;          // loader mapping (32x8)
    int pl = (t % 16) * 2;                 // this thread's 2 p's
    int cl = (t / 16) * 2;                 // this thread's 2 c's
    float acc[2][2] = {{0.f, 0.f}, {0.f, 0.f}};
    for (int k0 = 0; k0 < CC; k0 += 32) {
        #pragma unroll
        for (int r = 0; r < 4; ++r)
            Ws[ty + 8*r][tx] = Wx[(size_t)(c0 + ty + 8*r) * CC + k0 + tx];
        #pragma unroll
        for (int r = 0; r < 4; ++r) {
            int p = p0 + tx, k = k0 + ty + 8*r;
            Xs[ty + 8*r][tx] = (p < PP) ? X[((size_t)b * CC + k) * PP + p] : 0.f;
        }
        __syncthreads();
        #pragma unroll
        for (int k = 0; k < 32; ++k) {
            float w0 = Ws[cl][k], w1 = Ws[cl + 1][k];
            float x0 = Xs[k][pl], x1 = Xs[k][pl + 1];
            acc[0][0] += w0 * x0; acc[0][1] += w0 * x1;
            acc[1][0] += w1 * x0; acc[1][1] += w1 * x1;
        }
        __syncthreads();
    }
    #pragma unroll
    for (int i = 0; i < 2; ++i)
        #pragma unroll
        for (int j = 0; j < 2; ++j) {
            int c = c0 + cl + i, p = p0 + pl + j;
            if (p < PP) A[((size_t)b * PP + p) * CC + c] = acc[i][j] + b_in[c];
        }
}

// ---------------------------------------------------------------------------
// Kernel 2: one anti-diagonal step. One 256-thread WG per (seq, cell).
//   window:  h[c] = sum_{q in [0..px]x[0..py]} z*softmax_c(z),
//            z = relu(a_cur + U[:,q]); computed transcendental-free via
//            exp(z) = max(Ea*EU, 1),  z*exp(z) = max(a+U,0)*Ea*EU.
//   matvec:  U_new = Wh @ h  (WhT coalesced), EU_new = exp(U_new).
// ---------------------------------------------------------------------------
__global__ __launch_bounds__(256) void diag_step(
    const float* __restrict__ A, const float* __restrict__ WhT,
    float* __restrict__ U, float* __restrict__ EU,
    float* __restrict__ Hst, int d) {
    __shared__ float als[CC], eals[CC], hred[4][CC], hls[CC];
    int lo = (d <= 13) ? 0 : (d - 13);
    int s  = (int)blockIdx.x & 7;        // sequence: m*2 + b
    int ci = (int)blockIdx.x >> 3;
    int px = lo + ci, py = d - px;
    int m = s >> 1, b = s & 1;
    int fi = (m & 2) ? (13 - px) : px;   // flip for mode's scan coords
    int fj = (m & 1) ? (13 - py) : py;
    int t = threadIdx.x;

    const float* acur = A + ((size_t)b * PP + fi * WW + fj) * CC;
    for (int i = t; i < CC; i += 256) {
        float a = acur[i];
        als[i] = a; eals[i] = expf(a);
    }
    __syncthreads();

    int wave = t >> 6, lane = t & 63;
    int cb = lane * 4;                   // channels cb..cb+3 and cb+256..cb+259
    float ar[8], er[8];
    #pragma unroll
    for (int j = 0; j < 4; ++j) {
        ar[j]     = als[cb + j];       er[j]     = eals[cb + j];
        ar[4 + j] = als[cb + 256 + j]; er[4 + j] = eals[cb + 256 + j];
    }
    float hacc[8] = {0.f,0.f,0.f,0.f,0.f,0.f,0.f,0.f};
    int wy = py + 1;
    int npix = (px + 1) * wy;
    const float* Ub = U  + (size_t)s * PP * CC;
    const float* Eb = EU + (size_t)s * PP * CC;

    for (int w0 = wave; w0 < npix; w0 += 4) {
        int x = w0 / wy, y = w0 - x * wy;
        int qp = x * WW + y;
        float4 u0, u1, e0, e1;
        if (w0 != npix - 1) {            // last linear index == (px,py) itself
            const float4* up = (const float4*)(Ub + (size_t)qp * CC + cb);
            const float4* ep = (const float4*)(Eb + (size_t)qp * CC + cb);
            u0 = up[0]; u1 = up[64];     // +256 floats
            e0 = ep[0]; e1 = ep[64];
        } else {                          // self pixel: U=0, exp(U)=1
            u0 = make_float4(0.f,0.f,0.f,0.f); u1 = u0;
            e0 = make_float4(1.f,1.f,1.f,1.f); e1 = e0;
        }
        float uu[8] = {u0.x,u0.y,u0.z,u0.w,u1.x,u1.y,u1.z,u1.w};
        float ee[8] = {e0.x,e0.y,e0.z,e0.w,e1.x,e1.y,e1.z,e1.w};
        float ds = 0.f, tl[8];
        #pragma unroll
        for (int j = 0; j < 8; ++j) {
            float sv = ar[j] + uu[j];       // a + U
            float pv = er[j] * ee[j];       // exp(a+U)
            ds += fmaxf(pv, 1.0f);          // exp(relu(a+U))
            tl[j] = fmaxf(sv, 0.0f) * pv;   // z * exp(z)
        }
        #pragma unroll
        for (int off = 32; off; off >>= 1) ds += __shfl_xor(ds, off, 64);
        float rd = 1.0f / ds;
        #pragma unroll
        for (int j = 0; j < 8; ++j) hacc[j] += tl[j] * rd;
    }

    #pragma unroll
    for (int j = 0; j < 4; ++j) {
        hred[wave][cb + j]       = hacc[j];
        hred[wave][cb + 256 + j] = hacc[4 + j];
    }
    __syncthreads();

    int cell = px * WW + py;
    size_t obase = ((size_t)s * PP + cell) * CC;
    for (int i = t; i < CC; i += 256) {
        float h = hred[0][i] + hred[1][i] + hred[2][i] + hred[3][i];
        hls[i] = h;
        Hst[obase + i] = h;
    }
    __syncthreads();

    // U_new[c] = sum_k WhT[k][c] * h[k]; coalesced across threads.
    float a0 = 0.f, a1 = 0.f;
    int c0 = t, c1 = t + 256;
    for (int k = 0; k < CC; ++k) {
        float h = hls[k];
        a0 += WhT[(size_t)k * CC + c0] * h;
        a1 += WhT[(size_t)k * CC + c1] * h;
    }
    U[obase + c0] = a0; EU[obase + c0] = expf(a0);
    U[obase + c1] = a1; EU[obase + c1] = expf(a1);
}

// ---------------------------------------------------------------------------
// Kernel 3: Y[b][p][c] = sum_k Wo[c][k] * (sum_m Hst[m*2+b][p][k]) + 4*b_out[c]
// ---------------------------------------------------------------------------
__global__ __launch_bounds__(256) void gemm_y(
    const float* __restrict__ Wo, const float* __restrict__ Hst,
    const float* __restrict__ b_out, float* __restrict__ Y) {
    __shared__ float Ws[32][33], Hs[32][33];
    int b  = blockIdx.z;
    int c0 = blockIdx.x * 32, p0 = blockIdx.y * 32;
    int t  = threadIdx.x;
    int tx = t % 32, ty = t / 32;
    int pl = (t % 16) * 2;
    int cl = (t / 16) * 2;
    float acc[2][2] = {{0.f, 0.f}, {0.f, 0.f}};
    for (int k0 = 0; k0 < CC; k0 += 32) {
        #pragma unroll
        for (int r = 0; r < 4; ++r)
            Ws[ty + 8*r][tx] = Wo[(size_t)(c0 + ty + 8*r) * CC + k0 + tx];
        #pragma unroll
        for (int r = 0; r < 4; ++r) {
            int p = p0 + ty + 8*r;
            float v = 0.f;
            if (p < PP) {
                size_t base = (size_t)p * CC + k0 + tx;
                v = Hst[((size_t)(0*2 + b) * PP) * CC + base]
                  + Hst[((size_t)(1*2 + b) * PP) * CC + base]
                  + Hst[((size_t)(2*2 + b) * PP) * CC + base]
                  + Hst[((size_t)(3*2 + b) * PP) * CC + base];
            }
            Hs[tx][ty + 8*r] = v;   // Hs[k][p]
        }
        __syncthreads();
        #pragma unroll
        for (int k = 0; k < 32; ++k) {
            float w0 = Ws[cl][k], w1 = Ws[cl + 1][k];
            float h0 = Hs[k][pl], h1 = Hs[k][pl + 1];
            acc[0][0] += w0 * h0; acc[0][1] += w0 * h1;
            acc[1][0] += w1 * h0; acc[1][1] += w1 * h1;
        }
        __syncthreads();
    }
    #pragma unroll
    for (int i = 0; i < 2; ++i)
        #pragma unroll
        for (int j = 0; j < 2; ++j) {
            int c = c0 + cl + i, p = p0 + pl + j;
            if (p < PP) Y[((size_t)b * PP + p) * CC + c] = acc[i][j] + 4.0f * b_out[c];
        }
}

// ---------------------------------------------------------------------------
// Kernel 4: out[b][c][p] = softmax_c(Y[b][p][c]). One wave per (b,p).
// ---------------------------------------------------------------------------
__global__ __launch_bounds__(256) void softmax_out(
    const float* __restrict__ Y, float* __restrict__ out) {
    int wave = threadIdx.x >> 6, lane = threadIdx.x & 63;
    int idx = blockIdx.x * 4 + wave;      // 0..391
    if (idx >= BB * PP) return;
    int b = idx / PP, p = idx % PP;
    const float* y = Y + ((size_t)b * PP + p) * CC;
    float v[8];
    float mx = -3.4e38f;
    #pragma unroll
    for (int j = 0; j < 8; ++j) { v[j] = y[lane + 64*j]; mx = fmaxf(mx, v[j]); }
    #pragma unroll
    for (int off = 32; off; off >>= 1) mx = fmaxf(mx, __shfl_xor(mx, off, 64));
    float sum = 0.f;
    #pragma unroll
    for (int j = 0; j < 8; ++j) { v[j] = expf(v[j] - mx); sum += v[j]; }
    #pragma unroll
    for (int off = 32; off; off >>= 1) sum += __shfl_xor(sum, off, 64);
    float r = 1.0f / sum;
    #pragma unroll
    for (int j = 0; j < 8; ++j)
        out[((size_t)b * CC + lane + 64*j) * PP + p] = v[j] * r;
}

// ---------------------------------------------------------------------------
extern "C" void kernel_launch(void* const* d_in, const int* in_sizes, int n_in,
                              void* d_out, int out_size, void* d_ws, size_t ws_size,
                              hipStream_t stream) {
    const float* X     = (const float*)d_in[0];  // (2,512,14,14)
    const float* Wx    = (const float*)d_in[1];  // (512,512)
    const float* Wh    = (const float*)d_in[2];  // (512,512)
    const float* b_in  = (const float*)d_in[3];  // (512,)
    const float* Wo    = (const float*)d_in[4];  // (512,512)
    const float* b_out = (const float*)d_in[5];  // (512,)
    float* out = (float*)d_out;

    // workspace layout (floats); total ~12.3 MB
    float* ws  = (float*)d_ws;
    float* WhT = ws;                        // 512*512            = 262144
    float* A   = WhT + 262144;              // [2][196][512]      = 200704
    float* U   = A   + 200704;              // [8][196][512]      = 802816
    float* EU  = U   + 802816;              // [8][196][512]      = 802816
    float* Hst = EU  + 802816;              // [8][196][512]      = 802816
    float* Y   = Hst + 802816;              // [2][196][512]      = 200704

    hipLaunchKernelGGL(transpose_wh, dim3(16, 16), dim3(256), 0, stream, Wh, WhT);
    hipLaunchKernelGGL(gemm_a, dim3(16, 7, 2), dim3(256), 0, stream, Wx, X, b_in, A);

    for (int d = 0; d < 27; ++d) {
        int nc = (d <= 13) ? (d + 1) : (27 - d);
        hipLaunchKernelGGL(diag_step, dim3(nc * NSEQ), dim3(256), 0, stream,
                           A, WhT, U, EU, Hst, d);
    }

    hipLaunchKernelGGL(gemm_y, dim3(16, 7, 2), dim3(256), 0, stream, Wo, Hst, b_out, Y);
    hipLaunchKernelGGL(softmax_out, dim3(98), dim3(256), 0, stream, Y, out);
}

// Round 2
// 702.231 us; speedup vs baseline: 1.0776x; 1.0776x over previous
//
#include <hip/hip_runtime.h>
#include <hip/hip_bf16.h>

// Problem constants
#define BB 2
#define CC 512
#define HH 14
#define WW 14
#define PP 196      // H*W
#define NSEQ 8      // 4 modes x 2 batches

// ---------------------------------------------------------------------------
// Kernel 0: transpose Wh (512x512) -> WhT (coalesced matvec reads).
// ---------------------------------------------------------------------------
__global__ void transpose_wh(const float* __restrict__ Wh, float* __restrict__ WhT) {
    __shared__ float tile[32][33];
    int c0 = blockIdx.x * 32, k0 = blockIdx.y * 32;
    int tx = threadIdx.x % 32, ty = threadIdx.x / 32;   // 32x8
    #pragma unroll
    for (int r = 0; r < 4; ++r)
        tile[ty + 8*r][tx] = Wh[(size_t)(c0 + ty + 8*r) * CC + k0 + tx];
    __syncthreads();
    #pragma unroll
    for (int r = 0; r < 4; ++r)
        WhT[(size_t)(k0 + ty + 8*r) * CC + c0 + tx] = tile[tx][ty + 8*r];
}

// ---------------------------------------------------------------------------
// Kernel 1: A[b][p][c] = sum_k Wx[c][k] * X[b][k][p] + b_in[c]
// ---------------------------------------------------------------------------
__global__ __launch_bounds__(256) void gemm_a(
    const float* __restrict__ Wx, const float* __restrict__ X,
    const float* __restrict__ b_in, float* __restrict__ A) {
    __shared__ float Ws[32][33], Xs[32][33];
    int b  = blockIdx.z;
    int c0 = blockIdx.x * 32, p0 = blockIdx.y * 32;
    int t  = threadIdx.x;
    int tx = t % 32, ty = t / 32;
    int pl = (t % 16) * 2;
    int cl = (t / 16) * 2;
    float acc[2][2] = {{0.f, 0.f}, {0.f, 0.f}};
    for (int k0 = 0; k0 < CC; k0 += 32) {
        #pragma unroll
        for (int r = 0; r < 4; ++r)
            Ws[ty + 8*r][tx] = Wx[(size_t)(c0 + ty + 8*r) * CC + k0 + tx];
        #pragma unroll
        for (int r = 0; r < 4; ++r) {
            int p = p0 + tx, k = k0 + ty + 8*r;
            Xs[ty + 8*r][tx] = (p < PP) ? X[((size_t)b * CC + k) * PP + p] : 0.f;
        }
        __syncthreads();
        #pragma unroll
        for (int k = 0; k < 32; ++k) {
            float w0 = Ws[cl][k], w1 = Ws[cl + 1][k];
            float x0 = Xs[k][pl], x1 = Xs[k][pl + 1];
            acc[0][0] += w0 * x0; acc[0][1] += w0 * x1;
            acc[1][0] += w1 * x0; acc[1][1] += w1 * x1;
        }
        __syncthreads();
    }
    #pragma unroll
    for (int i = 0; i < 2; ++i)
        #pragma unroll
        for (int j = 0; j < 2; ++j) {
            int c = c0 + cl + i, p = p0 + pl + j;
            if (p < PP) A[((size_t)b * PP + p) * CC + c] = acc[i][j] + b_in[c];
        }
}

// ---------------------------------------------------------------------------
// Fused dataflow recurrence: one WG per (cell, seq), flag-based dependencies.
// ---------------------------------------------------------------------------
__device__ __forceinline__ void wave_wait(unsigned* f, int lane) {
    // Spin until *f != 0. RMW atomic executes at the coherence point, so the
    // poll can never cache a stale 0 in the (non-coherent) per-XCD L2.
    while (true) {
        unsigned p = 0;
        if (lane == 0) p = atomicAdd(f, 0u);
        p = (unsigned)__shfl((int)p, 0, 64);
        if (p) break;
        __builtin_amdgcn_s_sleep(2);
    }
}

__device__ __forceinline__ void do_pixel(const float* __restrict__ Uq,
                                         const float* __restrict__ Eq,
                                         int cb, const float* ar, const float* er,
                                         float* hacc) {
    const float4* up = (const float4*)(Uq + cb);
    const float4* ep = (const float4*)(Eq + cb);
    float4 u0 = up[0], u1 = up[64];     // +256 floats
    float4 e0 = ep[0], e1 = ep[64];
    float uu[8] = {u0.x,u0.y,u0.z,u0.w,u1.x,u1.y,u1.z,u1.w};
    float ee[8] = {e0.x,e0.y,e0.z,e0.w,e1.x,e1.y,e1.z,e1.w};
    float ds = 0.f, tl[8];
    #pragma unroll
    for (int j = 0; j < 8; ++j) {
        float sv = ar[j] + uu[j];       // a + U
        float pv = er[j] * ee[j];       // exp(a+U)
        ds += fmaxf(pv, 1.0f);          // exp(relu(a+U))
        tl[j] = fmaxf(sv, 0.0f) * pv;   // z * exp(z)
    }
    #pragma unroll
    for (int off = 32; off; off >>= 1) ds += __shfl_xor(ds, off, 64);
    float rd = 1.0f / ds;
    #pragma unroll
    for (int j = 0; j < 8; ++j) hacc[j] += tl[j] * rd;
}

__global__ __launch_bounds__(256, 8) void rnn_dataflow(
    const float* __restrict__ A, const float* __restrict__ WhT,
    float* __restrict__ U, float* __restrict__ EU,
    float* __restrict__ Hst, unsigned* __restrict__ flags) {
    __shared__ float als[CC], eals[CC], hred[4][CC], hls[CC];
    int s    = (int)blockIdx.x & 7;       // sequence: m*2 + b
    int cell = (int)blockIdx.x >> 3;      // raster cell; deps have smaller idx
    int px = cell / WW, py = cell % WW;
    int m = s >> 1, b = s & 1;
    int fi = (m & 2) ? (HH - 1 - px) : px;
    int fj = (m & 1) ? (WW - 1 - py) : py;
    int t = threadIdx.x;

    const float* acur = A + ((size_t)b * PP + fi * WW + fj) * CC;
    for (int i = t; i < CC; i += 256) {
        float a = acur[i];
        als[i] = a; eals[i] = expf(a);
    }
    __syncthreads();

    int wave = t >> 6, lane = t & 63;
    int cb = lane * 4;
    float ar[8], er[8], hacc[8];
    #pragma unroll
    for (int j = 0; j < 4; ++j) {
        ar[j]     = als[cb + j];       er[j]     = eals[cb + j];
        ar[4 + j] = als[cb + 256 + j]; er[4 + j] = eals[cb + 256 + j];
        hacc[j] = 0.f; hacc[4 + j] = 0.f;
    }

    const float* Ub = U  + (size_t)s * PP * CC;
    const float* Eb = EU + (size_t)s * PP * CC;
    unsigned* fb = flags + s * PP;

    // Phase A: bulk rectangle x<=px-1, y<=py-1 (ready once corner fires).
    if (px > 0 && py > 0) {
        wave_wait(fb + (px - 1) * WW + (py - 1), lane);
        int na = px * py;
        for (int idx = wave; idx < na; idx += 4) {
            int x = idx / py, y = idx - x * py;
            int qp = x * WW + y;
            do_pixel(Ub + (size_t)qp * CC, Eb + (size_t)qp * CC, cb, ar, er, hacc);
        }
    }
    // Phase B: strip x<=px-1, y=py.
    if (px > 0) {
        wave_wait(fb + (px - 1) * WW + py, lane);
        for (int x = wave; x < px; x += 4) {
            int qp = x * WW + py;
            do_pixel(Ub + (size_t)qp * CC, Eb + (size_t)qp * CC, cb, ar, er, hacc);
        }
    }
    // Phase C: strip x=px, y<=py-1.
    if (py > 0) {
        wave_wait(fb + px * WW + (py - 1), lane);
        for (int y = wave; y < py; y += 4) {
            int qp = px * WW + y;
            do_pixel(Ub + (size_t)qp * CC, Eb + (size_t)qp * CC, cb, ar, er, hacc);
        }
    }
    // Phase D: self pixel (h==0 there: U=0, exp(U)=1), one wave.
    if (wave == 0) {
        float ds = 0.f, tl[8];
        #pragma unroll
        for (int j = 0; j < 8; ++j) {
            float pv = er[j];
            ds += fmaxf(pv, 1.0f);
            tl[j] = fmaxf(ar[j], 0.0f) * pv;
        }
        #pragma unroll
        for (int off = 32; off; off >>= 1) ds += __shfl_xor(ds, off, 64);
        float rd = 1.0f / ds;
        #pragma unroll
        for (int j = 0; j < 8; ++j) hacc[j] += tl[j] * rd;
    }

    #pragma unroll
    for (int j = 0; j < 4; ++j) {
        hred[wave][cb + j]       = hacc[j];
        hred[wave][cb + 256 + j] = hacc[4 + j];
    }
    __syncthreads();

    size_t obase = ((size_t)s * PP + cell) * CC;
    for (int i = t; i < CC; i += 256) {
        float h = hred[0][i] + hred[1][i] + hred[2][i] + hred[3][i];
        hls[i] = h;
        Hst[obase + i] = h;
    }
    __syncthreads();

    // Matvec: U_new[c] = sum_k WhT[k][c]*h[k]; wave w owns channels
    // [128w,128w+128): per-thread 2 outputs, unroll-8 for load ILP.
    int c0 = wave * 128 + lane, c1 = c0 + 64;
    float a0 = 0.f, a1 = 0.f;
    #pragma unroll 8
    for (int k = 0; k < CC; ++k) {
        float h = hls[k];
        a0 += WhT[(size_t)k * CC + c0] * h;
        a1 += WhT[(size_t)k * CC + c1] * h;
    }
    U[obase + c0] = a0; EU[obase + c0] = expf(a0);
    U[obase + c1] = a1; EU[obase + c1] = expf(a1);

    __syncthreads();                      // barrier drains vmcnt: stores in L2
    if (t == 0) {
        __threadfence();                  // agent fence: write back past XCD L2
        atomicExch(fb + cell, 1u);        // publish
    }
}

// ---------------------------------------------------------------------------
// Kernel 3: Y[b][p][c] = sum_k Wo[c][k] * (sum_m Hst[m*2+b][p][k]) + 4*b_out[c]
// ---------------------------------------------------------------------------
__global__ __launch_bounds__(256) void gemm_y(
    const float* __restrict__ Wo, const float* __restrict__ Hst,
    const float* __restrict__ b_out, float* __restrict__ Y) {
    __shared__ float Ws[32][33], Hs[32][33];
    int b  = blockIdx.z;
    int c0 = blockIdx.x * 32, p0 = blockIdx.y * 32;
    int t  = threadIdx.x;
    int tx = t % 32, ty = t / 32;
    int pl = (t % 16) * 2;
    int cl = (t / 16) * 2;
    float acc[2][2] = {{0.f, 0.f}, {0.f, 0.f}};
    for (int k0 = 0; k0 < CC; k0 += 32) {
        #pragma unroll
        for (int r = 0; r < 4; ++r)
            Ws[ty + 8*r][tx] = Wo[(size_t)(c0 + ty + 8*r) * CC + k0 + tx];
        #pragma unroll
        for (int r = 0; r < 4; ++r) {
            int p = p0 + ty + 8*r;
            float v = 0.f;
            if (p < PP) {
                size_t base = (size_t)p * CC + k0 + tx;
                v = Hst[((size_t)(0*2 + b) * PP) * CC + base]
                  + Hst[((size_t)(1*2 + b) * PP) * CC + base]
                  + Hst[((size_t)(2*2 + b) * PP) * CC + base]
                  + Hst[((size_t)(3*2 + b) * PP) * CC + base];
            }
            Hs[tx][ty + 8*r] = v;
        }
        __syncthreads();
        #pragma unroll
        for (int k = 0; k < 32; ++k) {
            float w0 = Ws[cl][k], w1 = Ws[cl + 1][k];
            float h0 = Hs[k][pl], h1 = Hs[k][pl + 1];
            acc[0][0] += w0 * h0; acc[0][1] += w0 * h1;
            acc[1][0] += w1 * h0; acc[1][1] += w1 * h1;
        }
        __syncthreads();
    }
    #pragma unroll
    for (int i = 0; i < 2; ++i)
        #pragma unroll
        for (int j = 0; j < 2; ++j) {
            int c = c0 + cl + i, p = p0 + pl + j;
            if (p < PP) Y[((size_t)b * PP + p) * CC + c] = acc[i][j] + 4.0f * b_out[c];
        }
}

// ---------------------------------------------------------------------------
// Kernel 4: out[b][c][p] = softmax_c(Y[b][p][c]).
// ---------------------------------------------------------------------------
__global__ __launch_bounds__(256) void softmax_out(
    const float* __restrict__ Y, float* __restrict__ out) {
    int wave = threadIdx.x >> 6, lane = threadIdx.x & 63;
    int idx = blockIdx.x * 4 + wave;
    if (idx >= BB * PP) return;
    int b = idx / PP, p = idx % PP;
    const float* y = Y + ((size_t)b * PP + p) * CC;
    float v[8];
    float mx = -3.4e38f;
    #pragma unroll
    for (int j = 0; j < 8; ++j) { v[j] = y[lane + 64*j]; mx = fmaxf(mx, v[j]); }
    #pragma unroll
    for (int off = 32; off; off >>= 1) mx = fmaxf(mx, __shfl_xor(mx, off, 64));
    float sum = 0.f;
    #pragma unroll
    for (int j = 0; j < 8; ++j) { v[j] = expf(v[j] - mx); sum += v[j]; }
    #pragma unroll
    for (int off = 32; off; off >>= 1) sum += __shfl_xor(sum, off, 64);
    float r = 1.0f / sum;
    #pragma unroll
    for (int j = 0; j < 8; ++j)
        out[((size_t)b * CC + lane + 64*j) * PP + p] = v[j] * r;
}

// ---------------------------------------------------------------------------
extern "C" void kernel_launch(void* const* d_in, const int* in_sizes, int n_in,
                              void* d_out, int out_size, void* d_ws, size_t ws_size,
                              hipStream_t stream) {
    const float* X     = (const float*)d_in[0];
    const float* Wx    = (const float*)d_in[1];
    const float* Wh    = (const float*)d_in[2];
    const float* b_in  = (const float*)d_in[3];
    const float* Wo    = (const float*)d_in[4];
    const float* b_out = (const float*)d_in[5];
    float* out = (float*)d_out;

    float* ws  = (float*)d_ws;
    float* WhT = ws;                        // 262144
    float* A   = WhT + 262144;              // 200704
    float* U   = A   + 200704;              // 802816
    float* EU  = U   + 802816;              // 802816
    float* Hst = EU  + 802816;              // 802816
    float* Y   = Hst + 802816;              // 200704
    unsigned* flags = (unsigned*)(Y + 200704);  // 8*196 = 1568 words

    hipMemsetAsync(flags, 0, NSEQ * PP * sizeof(unsigned), stream);
    hipLaunchKernelGGL(transpose_wh, dim3(16, 16), dim3(256), 0, stream, Wh, WhT);
    hipLaunchKernelGGL(gemm_a, dim3(16, 7, 2), dim3(256), 0, stream, Wx, X, b_in, A);

    hipLaunchKernelGGL(rnn_dataflow, dim3(PP * NSEQ), dim3(256), 0, stream,
                       A, WhT, U, EU, Hst, flags);

    hipLaunchKernelGGL(gemm_y, dim3(16, 7, 2), dim3(256), 0, stream, Wo, Hst, b_out, Y);
    hipLaunchKernelGGL(softmax_out, dim3(98), dim3(256), 0, stream, Y, out);
}